// Round 14
// baseline (3167.401 us; speedup 1.0000x reference)
//
#include <hip/hip_runtime.h>
#include <cstdint>
#include <cstddef>

namespace {

constexpr int H    = 300;
constexpr int B    = 128;
constexpr int T    = 512;
constexpr int NVOC = 2514;
constexpr int KP   = 304;    // padded K pitch for packed bf16 hi/lo planes

typedef __attribute__((ext_vector_type(8))) short  short8;
typedef __attribute__((ext_vector_type(4))) float  f32x4;

__device__ __forceinline__ float sigm(float x)     { return 1.f / (1.f + __expf(-x)); }
__device__ __forceinline__ float tanhfast(float x) { return 1.f - 2.f / (__expf(2.f*x) + 1.f); }

__device__ __forceinline__ unsigned short bf16_rn(float f) {
    unsigned u = __float_as_uint(f);
    u += 0x7FFFu + ((u >> 16) & 1u);
    return (unsigned short)(u >> 16);
}
__device__ __forceinline__ float bf16_f(unsigned short s) {
    return __uint_as_float(((unsigned)s) << 16);
}
// packed value = bf16hi | (bf16lo << 16)
__device__ __forceinline__ unsigned pack_hl(float v) {
    const unsigned short hi = bf16_rn(v);
    const unsigned short lo = bf16_rn(v - bf16_f(hi));
    return (unsigned)hi | ((unsigned)lo << 16);
}

// packed h layout: idx(t, hg, b, u) = ((t*15 + hg)*128 + b)*20 + u   (u32 elems)
constexpr int TSEG = 15 * 128 * 20;   // u32 per t-slice (38400)

// sentinel: low16 = 0x7FB0 is a bf16 NaN -> impossible as the hi-plane of |h|<1
constexpr unsigned SENTP = 0x7FB07FB0u;

// ---------------------------------------------------------------------------
// Sentinel fill for packed h buffers
// ---------------------------------------------------------------------------
__global__ __launch_bounds__(256)
void sentinel_fill(uint4* __restrict__ p, size_t n4)
{
    const uint4 s = make_uint4(SENTP, SENTP, SENTP, SENTP);
    size_t i = (size_t)blockIdx.x * blockDim.x + threadIdx.x;
    const size_t stride = (size_t)gridDim.x * blockDim.x;
    for (; i < n4; i += stride) p[i] = s;
}

// ---------------------------------------------------------------------------
// Preconvert fp32 [rows][300] -> packed u32 [rows][KP] (hi|lo<<16), pad 0.
// ---------------------------------------------------------------------------
__global__ __launch_bounds__(256)
void preconv(const float* __restrict__ src, unsigned* __restrict__ dst, int rows)
{
    const size_t n = (size_t)rows * KP;
    for (size_t i = (size_t)blockIdx.x * 256 + threadIdx.x; i < n;
         i += (size_t)gridDim.x * 256) {
        const int c = (int)(i % KP), r = (int)(i / KP);
        dst[i] = (c < H) ? pack_hl(src[(size_t)r * H + c]) : 0u;
    }
}

// ---------------------------------------------------------------------------
// Logits GEMM v14: 2-PASS split MFMA (Ah*Wh + Al*Wh; the Ah*Wl term —
// sigma ~2.4e-4, max ~1.3e-3 over 165M outputs — is dropped). W lo-plane
// staging removed entirely: -33% MFMA, -25% staging vs round 13.
// A = packed h2 ([t][hg][b][20] u32), W = packed Wout ([NVOC][KP] u32).
// ---------------------------------------------------------------------------
__global__ __launch_bounds__(256)
void gemm_pk(const unsigned* __restrict__ Apk, const unsigned* __restrict__ Wpk,
             const float* __restrict__ b1, float* __restrict__ out, int N)
{
    __shared__ __align__(16) unsigned short Ah[128][40], Al[128][40];
    __shared__ __align__(16) unsigned short Wh[128][40];

    const int tid = threadIdx.x;
    const int m0 = blockIdx.y * 128, n0 = blockIdx.x * 128;
    const int rl = tid >> 1, cb = (tid & 1) * 16;

    const int m = m0 + rl;
    const unsigned* aptr = Apk + (size_t)(m & 511) * TSEG + (m >> 9) * 20;
    const int nrow = n0 + rl;
    const unsigned* wptr = Wpk + (size_t)nrow * KP;
    const bool nok = (nrow < N);

    const int wv = tid >> 6, lane = tid & 63;
    const int mw = (wv >> 1) * 64, nw = (wv & 1) * 64;
    const int kg = lane >> 4, mm = lane & 15;

    f32x4 acc[4][4];
#pragma unroll
    for (int i = 0; i < 4; ++i)
#pragma unroll
        for (int j = 0; j < 4; ++j) acc[i][j] = (f32x4){0.f, 0.f, 0.f, 0.f};

    for (int kt = 0; kt < 10; ++kt) {
        uint4 pa[4], pw[4];
#pragma unroll
        for (int j = 0; j < 4; ++j) {
            const int col = kt * 32 + cb + j * 4;
            pa[j] = (col < 300)
                  ? *(const uint4*)(aptr + (col / 20) * 2560 + col % 20)
                  : make_uint4(0, 0, 0, 0);
            pw[j] = (nok && col < KP) ? *(const uint4*)(wptr + col)
                                      : make_uint4(0, 0, 0, 0);
        }
        __syncthreads();
#pragma unroll
        for (int j = 0; j < 4; ++j) {
            const int cc = cb + j * 4;
            *(uint2*)&Ah[rl][cc] = make_uint2((pa[j].x & 0xFFFFu) | (pa[j].y << 16),
                                              (pa[j].z & 0xFFFFu) | (pa[j].w << 16));
            *(uint2*)&Al[rl][cc] = make_uint2((pa[j].x >> 16) | (pa[j].y & 0xFFFF0000u),
                                              (pa[j].z >> 16) | (pa[j].w & 0xFFFF0000u));
            *(uint2*)&Wh[rl][cc] = make_uint2((pw[j].x & 0xFFFFu) | (pw[j].y << 16),
                                              (pw[j].z & 0xFFFFu) | (pw[j].w << 16));
        }
        __syncthreads();

        short8 fah[4], fal[4], fbh[4];
#pragma unroll
        for (int f = 0; f < 4; ++f) {
            fah[f] = *(const short8*)&Ah[mw + f*16 + mm][kg*8];
            fal[f] = *(const short8*)&Al[mw + f*16 + mm][kg*8];
            fbh[f] = *(const short8*)&Wh[nw + f*16 + mm][kg*8];
        }
#pragma unroll
        for (int mf = 0; mf < 4; ++mf)
#pragma unroll
            for (int nf = 0; nf < 4; ++nf) {
                acc[mf][nf] = __builtin_amdgcn_mfma_f32_16x16x32_bf16(fah[mf], fbh[nf], acc[mf][nf], 0, 0, 0);
                acc[mf][nf] = __builtin_amdgcn_mfma_f32_16x16x32_bf16(fal[mf], fbh[nf], acc[mf][nf], 0, 0, 0);
            }
    }

    float bias[4];
#pragma unroll
    for (int nf = 0; nf < 4; ++nf) {
        const int n = n0 + nw + nf*16 + mm;
        bias[nf] = (n < N) ? b1[n] : 0.f;
    }
    const int qr = lane >> 4;
#pragma unroll
    for (int mf = 0; mf < 4; ++mf) {
        const int row = m0 + mw + mf*16 + qr*4;
        float* orow = out + (size_t)row * N;
#pragma unroll
        for (int nf = 0; nf < 4; ++nf) {
            const int n = n0 + nw + nf*16 + mm;
            if (n < N) {
#pragma unroll
                for (int r = 0; r < 4; ++r)
                    orow[(size_t)r * N + n] = acc[mf][nf][r] + bias[nf];
            }
        }
    }
}

// ---------------------------------------------------------------------------
// v14 fused recurrence — UNCHANGED from round 13 (at protocol floor,
// 4.81 us/iter x 513; three protocol rewrites in a row returned <=10%).
// ---------------------------------------------------------------------------
constexpr int HGC = 15;
constexpr int BGC = 16;
constexpr int NWG = HGC * BGC;   // 240
constexpr int A2OFF  = 20480;    // h2 region within a parity
constexpr int EOFF   = 40960;    // e region within a parity
constexpr int APARF  = 61440;    // bytes per parity (h1 + h2 + e)
constexpr int GDOFF  = 2 * APARF;            // 122880
constexpr int TOKOFF = GDOFF + 10*8*16*4;    // 128000
constexpr int FLDS   = TOKOFF + 8*512*4;     // 144384 B

struct StageCtx {
    size_t   src64[5];
    int      aoffHi[5];
    unsigned pend0;
};

__device__ __forceinline__ void stage_init(StageCtx& S, int lane, int bg,
                                           int base_hg, int nchunks, int region)
{
    const int words = nchunks * 80;   // 80 u64-pairs per (hg,bg) chunk
    S.pend0 = 0;
#pragma unroll
    for (int j = 0; j < 5; ++j) {
        const int s = lane + 64 * j;
        const bool ok = (s < words);
        const int chunk = ok ? s / 80 : 0, rem = ok ? s % 80 : 0;
        const int hg = base_hg + chunk;
        S.src64[j] = (size_t)(hg * 128 + bg * 8) * 10 + rem;
        const int u2 = rem * 2, b_loc = u2 / 20, u = u2 % 20;
        const int k = hg * 20 + u;
        S.aoffHi[j] = region + ((k >> 5) * 8 + ((k >> 3) & 3)) * 256
                    + b_loc * 16 + (k & 7) * 2;
        if (ok) S.pend0 |= 1u << j;
    }
}

__device__ __forceinline__ void stage_poll(const StageCtx& S,
                                           const unsigned* __restrict__ slice,
                                           unsigned char* Ap)
{
    const unsigned long long* s64 = (const unsigned long long*)slice;
    unsigned long long val[5];
    unsigned pend = S.pend0;
    while (__any(pend != 0)) {
        unsigned long long w[5];
#pragma unroll
        for (int j = 0; j < 5; ++j)
            if (pend & (1u << j))
                w[j] = __hip_atomic_load(s64 + S.src64[j], __ATOMIC_RELAXED,
                                         __HIP_MEMORY_SCOPE_AGENT);
#pragma unroll
        for (int j = 0; j < 5; ++j)
            if (pend & (1u << j)) {
                const unsigned long long x = w[j];
                if ((unsigned)x != SENTP && (unsigned)(x >> 32) != SENTP) {
                    val[j] = x; pend &= ~(1u << j);
                }
            }
    }
#pragma unroll
    for (int j = 0; j < 5; ++j)
        if (S.pend0 & (1u << j)) {
            const unsigned p0 = (unsigned)val[j], p1 = (unsigned)(val[j] >> 32);
            *(unsigned*)(Ap + S.aoffHi[j])        = (p0 & 0xFFFFu) | (p1 << 16);
            *(unsigned*)(Ap + S.aoffHi[j] + 1024) = (p0 >> 16) | (p1 & 0xFFFF0000u);
        }
}

struct ECtx { int b[3]; int koff[3]; int aoff[3]; bool ok[3]; };

__device__ __forceinline__ void estage_init(ECtx& E, int tid)
{
#pragma unroll
    for (int j = 0; j < 3; ++j) {
        const int es = tid + 512 * j;
        E.ok[j] = (es < 1216);   // 8 b x 152 k-pairs (incl. 2 zero-pad pairs)
        const int bb = E.ok[j] ? es / 152 : 0;
        const int kp = E.ok[j] ? es % 152 : 0;
        const int k  = kp * 2;
        E.b[j]    = bb;
        E.koff[j] = k;
        E.aoff[j] = EOFF + ((k >> 5) * 8 + ((k >> 3) & 3)) * 256
                  + bb * 16 + (k & 7) * 2;
    }
}

__device__ __forceinline__ void estage(const ECtx& E, const int* __restrict__ tokL,
                                       const unsigned* __restrict__ embcv, int it,
                                       unsigned char* Ap)
{
#pragma unroll
    for (int j = 0; j < 3; ++j)
        if (E.ok[j]) {
            const int tok = tokL[E.b[j] * 512 + it];
            const unsigned long long w = *(const unsigned long long*)
                (embcv + (size_t)tok * KP + E.koff[j]);
            const unsigned p0 = (unsigned)w, p1 = (unsigned)(w >> 32);
            *(unsigned*)(Ap + E.aoff[j])        = (p0 & 0xFFFFu) | (p1 << 16);
            *(unsigned*)(Ap + E.aoff[j] + 1024) = (p0 >> 16) | (p1 & 0xFFFF0000u);
        }
}

// ---- L0 wave: one n-tile (4 units); e@Wih0 (3-pass) + h1@Whh0 (2-pass) ----
__device__ void fused_L0(int lane, int nt, int hg, int bg,
                         const unsigned* __restrict__ embcv,
                         const float* __restrict__ Wih0,
                         const float* __restrict__ Whh0,
                         const float* __restrict__ bih0,
                         const float* __restrict__ bhh0,
                         unsigned* __restrict__ h1p,
                         const unsigned* __restrict__ ssrc, int sreg, int sbase,
                         int snch, int sdel,
                         const ECtx& E, const int* __restrict__ tokL,
                         unsigned char* __restrict__ Abuf, float (*gd)[8][16])
{
    const int kg = lane >> 4, mm = lane & 15;

    short8 bhh[10], bih[10], bil[10];
#pragma unroll
    for (int kt = 0; kt < 10; ++kt) {
        const int c = nt * 16 + mm;
        const int grow = (c & 3) * H + hg * 20 + (c >> 2);
        short8 h_, ih_, il_;
#pragma unroll
        for (int e = 0; e < 8; ++e) {
            const int k = kt * 32 + kg * 8 + e;
            const float vh = (k < H) ? Whh0[(size_t)grow * H + k] : 0.f;
            const float vi = (k < H) ? Wih0[(size_t)grow * H + k] : 0.f;
            h_[e] = (short)bf16_rn(vh);
            const unsigned short i16 = bf16_rn(vi);
            ih_[e] = (short)i16;
            il_[e] = (short)bf16_rn(vi - bf16_f(i16));
        }
        bhh[kt] = h_; bih[kt] = ih_; bil[kt] = il_;
    }

    StageCtx S; stage_init(S, lane, bg, sbase, snch, sreg);

    const bool upd = lane < 32;
    const int b_u = lane >> 2, u4 = lane & 3;
    const int u_loc = nt * 4 + u4;
    float bias[4];
#pragma unroll
    for (int g = 0; g < 4; ++g)
        bias[g] = bih0[g * H + hg * 20 + u_loc] + bhh0[g * H + hg * 20 + u_loc];
    float cst = 0.f;
    unsigned* hst = h1p + ((size_t)hg * 128 + bg * 8 + b_u) * 20 + u_loc;

    for (int it = 0; it <= T; ++it) {
        unsigned char* Ap = Abuf + (it & 1) * APARF;
        if (it < T) estage(E, tokL, embcv, it, Ap);
        if (it >= sdel) stage_poll(S, ssrc + (size_t)(it - sdel) * TSEG, Ap);
        __syncthreads();

        if (it < T) {
            f32x4 acc = (f32x4){0.f, 0.f, 0.f, 0.f};
#pragma unroll
            for (int kt = 0; kt < 10; ++kt) {
                const int boff = (kt * 8 + kg) * 256 + mm * 16;
                const short8 eh = *(const short8*)(Ap + EOFF + boff);
                const short8 el = *(const short8*)(Ap + EOFF + boff + 1024);
                const short8 hh = *(const short8*)(Ap + boff);
                const short8 hl = *(const short8*)(Ap + boff + 1024);
                acc = __builtin_amdgcn_mfma_f32_16x16x32_bf16(eh, bih[kt], acc, 0, 0, 0);
                acc = __builtin_amdgcn_mfma_f32_16x16x32_bf16(el, bih[kt], acc, 0, 0, 0);
                acc = __builtin_amdgcn_mfma_f32_16x16x32_bf16(eh, bil[kt], acc, 0, 0, 0);
                acc = __builtin_amdgcn_mfma_f32_16x16x32_bf16(hh, bhh[kt], acc, 0, 0, 0);
                acc = __builtin_amdgcn_mfma_f32_16x16x32_bf16(hl, bhh[kt], acc, 0, 0, 0);
            }
            if (lane < 32) {
                const int br = (lane >> 4) * 4;
#pragma unroll
                for (int r = 0; r < 4; ++r) gd[nt][br + r][mm] = acc[r];
            }
            if (upd) {
                const float* g4 = &gd[nt][b_u][u4 * 4];
                const float gi = bias[0] + g4[0], gf = bias[1] + g4[1];
                const float gz = bias[2] + g4[2], go = bias[3] + g4[3];
                const float iG = sigm(gi), fG = sigm(gf);
                const float zG = tanhfast(gz), oG = sigm(go);
                cst = fmaf(fG, cst, iG * zG);
                const float hv = oG * tanhfast(cst);
                __hip_atomic_store(hst + (size_t)it * TSEG, pack_hl(hv),
                                   __ATOMIC_RELAXED, __HIP_MEMORY_SCOPE_AGENT);
            }
        }
    }
}

// ---- L1 wave: NTL tiles; h1@Wih1 (2-pass) + h2@Whh1 (2-pass) per tile ------
template<int NTL>
__device__ void fused_L1(int lane, int t0, int hg, int bg,
                         const unsigned* __restrict__ embcv,
                         const float* __restrict__ Wih1,
                         const float* __restrict__ Whh1,
                         const float* __restrict__ bih1,
                         const float* __restrict__ bhh1,
                         unsigned* __restrict__ h2p,
                         const unsigned* __restrict__ ssrc, int sreg, int sbase,
                         int snch, int sdel,
                         const ECtx& E, const int* __restrict__ tokL,
                         unsigned char* __restrict__ Abuf, float (*gd)[8][16])
{
    const int kg = lane >> 4, mm = lane & 15;

    short8 bi[NTL][10], bh[NTL][10];
#pragma unroll
    for (int t = 0; t < NTL; ++t)
#pragma unroll
        for (int kt = 0; kt < 10; ++kt) {
            const int c = (t0 + t) * 16 + mm;
            const int grow = (c & 3) * H + hg * 20 + (c >> 2);
            short8 i_, h_;
#pragma unroll
            for (int e = 0; e < 8; ++e) {
                const int k = kt * 32 + kg * 8 + e;
                i_[e] = (short)bf16_rn((k < H) ? Wih1[(size_t)grow * H + k] : 0.f);
                h_[e] = (short)bf16_rn((k < H) ? Whh1[(size_t)grow * H + k] : 0.f);
            }
            bi[t][kt] = i_; bh[t][kt] = h_;
        }

    StageCtx S; stage_init(S, lane, bg, sbase, snch, sreg);

    const bool upd = lane < NTL * 32;
    const int tile = lane >> 5, lidx = lane & 31;
    const int b_u = lidx >> 2, u4 = lidx & 3;
    const int ntg = t0 + ((NTL > 1) ? tile : 0);
    const int u_loc = ntg * 4 + u4;
    float bias[4];
#pragma unroll
    for (int g = 0; g < 4; ++g)
        bias[g] = bih1[g * H + hg * 20 + u_loc] + bhh1[g * H + hg * 20 + u_loc];
    float cst = 0.f;
    unsigned* hst = h2p + ((size_t)hg * 128 + bg * 8 + b_u) * 20 + u_loc;

    for (int it = 0; it <= T; ++it) {
        unsigned char* Ap = Abuf + (it & 1) * APARF;
        if (it < T) estage(E, tokL, embcv, it, Ap);
        if (it >= sdel) stage_poll(S, ssrc + (size_t)(it - sdel) * TSEG, Ap);
        __syncthreads();

        if (it >= 1) {
            f32x4 acc[NTL];
#pragma unroll
            for (int t = 0; t < NTL; ++t) acc[t] = (f32x4){0.f, 0.f, 0.f, 0.f};
#pragma unroll
            for (int kt = 0; kt < 10; ++kt) {
                const int boff = (kt * 8 + kg) * 256 + mm * 16;
                const short8 x1h = *(const short8*)(Ap + boff);
                const short8 x1l = *(const short8*)(Ap + boff + 1024);
                const short8 x2h = *(const short8*)(Ap + A2OFF + boff);
                const short8 x2l = *(const short8*)(Ap + A2OFF + boff + 1024);
#pragma unroll
                for (int t = 0; t < NTL; ++t) {
                    acc[t] = __builtin_amdgcn_mfma_f32_16x16x32_bf16(x1h, bi[t][kt], acc[t], 0, 0, 0);
                    acc[t] = __builtin_amdgcn_mfma_f32_16x16x32_bf16(x1l, bi[t][kt], acc[t], 0, 0, 0);
                    acc[t] = __builtin_amdgcn_mfma_f32_16x16x32_bf16(x2h, bh[t][kt], acc[t], 0, 0, 0);
                    acc[t] = __builtin_amdgcn_mfma_f32_16x16x32_bf16(x2l, bh[t][kt], acc[t], 0, 0, 0);
                }
            }
            if (lane < 32) {
                const int br = (lane >> 4) * 4;
#pragma unroll
                for (int t = 0; t < NTL; ++t)
#pragma unroll
                    for (int r = 0; r < 4; ++r) gd[5 + t0 + t][br + r][mm] = acc[t][r];
            }
            if (upd) {
                const float* g4 = &gd[5 + ntg][b_u][u4 * 4];
                const float gi = bias[0] + g4[0], gf = bias[1] + g4[1];
                const float gz = bias[2] + g4[2], go = bias[3] + g4[3];
                const float iG = sigm(gi), fG = sigm(gf);
                const float zG = tanhfast(gz), oG = sigm(go);
                cst = fmaf(fG, cst, iG * zG);
                const float hv = oG * tanhfast(cst);
                __hip_atomic_store(hst + (size_t)(it - 1) * TSEG, pack_hl(hv),
                                   __ATOMIC_RELAXED, __HIP_MEMORY_SCOPE_AGENT);
            }
        }
    }
}

__global__ __launch_bounds__(512, 2)
void lstm_fused(const int* __restrict__ x,
                const unsigned* __restrict__ embcv,
                const float* __restrict__ Wih0, const float* __restrict__ Whh0,
                const float* __restrict__ bih0, const float* __restrict__ bhh0,
                const float* __restrict__ Wih1, const float* __restrict__ Whh1,
                const float* __restrict__ bih1, const float* __restrict__ bhh1,
                unsigned* __restrict__ h1p, unsigned* __restrict__ h2p)
{
    extern __shared__ unsigned char smem[];
    unsigned char* Abuf = smem;
    float (*gd)[8][16] = (float(*)[8][16])(smem + GDOFF);
    int* tokL = (int*)(smem + TOKOFF);

    const int tid = threadIdx.x, wv = tid >> 6, lane = tid & 63;
    const int hg = blockIdx.x % HGC, bg = blockIdx.x / HGC;

    for (int i = tid; i < FLDS / 16; i += 512)
        ((uint4*)smem)[i] = make_uint4(0, 0, 0, 0);
    __syncthreads();
    // preload tokens for this block's 8 batch rows: tokL[b][t]
    for (int idx = tid; idx < 8 * 512; idx += 512) {
        const int b = idx >> 9, tt = idx & 511;
        tokL[idx] = x[(size_t)(bg * 8 + b) * T + tt];
    }
    __syncthreads();

    ECtx E; estage_init(E, tid);

    // staging role: wv0-3 -> h1 quarters (d=1), wv4-7 -> h2 quarters (d=2)
    const int      sreg  = (wv < 4) ? 0 : A2OFF;
    const unsigned* ssrc = (wv < 4) ? h1p : h2p;
    const int      sbase = (wv & 3) * 4;
    const int      snch  = ((wv & 3) == 3) ? 3 : 4;
    const int      sdel  = (wv < 4) ? 1 : 2;

    if (wv < 5)
        fused_L0(lane, wv, hg, bg, embcv, Wih0, Whh0, bih0, bhh0, h1p,
                 ssrc, sreg, sbase, snch, sdel, E, tokL, Abuf, gd);
    else if (wv == 5)
        fused_L1<2>(lane, 0, hg, bg, embcv, Wih1, Whh1, bih1, bhh1, h2p,
                    ssrc, sreg, sbase, snch, sdel, E, tokL, Abuf, gd);
    else if (wv == 6)
        fused_L1<2>(lane, 2, hg, bg, embcv, Wih1, Whh1, bih1, bhh1, h2p,
                    ssrc, sreg, sbase, snch, sdel, E, tokL, Abuf, gd);
    else
        fused_L1<1>(lane, 4, hg, bg, embcv, Wih1, Whh1, bih1, bhh1, h2p,
                    ssrc, sreg, sbase, snch, sdel, E, tokL, Abuf, gd);
}

} // anonymous namespace

// ---------------------------------------------------------------------------
extern "C" void kernel_launch(void* const* d_in, const int* in_sizes, int n_in,
                              void* d_out, int out_size, void* d_ws, size_t ws_size,
                              hipStream_t stream)
{
    const int*   x    = (const int*)  d_in[0];
    const float* emb  = (const float*)d_in[1];
    const float* Wih0 = (const float*)d_in[2];
    const float* Whh0 = (const float*)d_in[3];
    const float* bih0 = (const float*)d_in[4];
    const float* bhh0 = (const float*)d_in[5];
    const float* Wih1 = (const float*)d_in[6];
    const float* Whh1 = (const float*)d_in[7];
    const float* bih1 = (const float*)d_in[8];
    const float* bhh1 = (const float*)d_in[9];
    const float* Wout = (const float*)d_in[10];
    const float* bout = (const float*)d_in[11];

    float* out = (float*)d_out;

    // d_ws layout: h1p, h2p (packed u32, 78.64 MB each), embcv, wcvo
    unsigned* h1p   = (unsigned*)d_ws;
    unsigned* h2p   = h1p + (size_t)T * TSEG;
    unsigned* embcv = h2p + (size_t)T * TSEG;
    unsigned* wcvo  = embcv + (size_t)NVOC * KP;

    // sentinel-fill both packed h buffers (data-as-flag protocol)
    const size_t nh4 = 2 * (size_t)T * TSEG / 4;
    sentinel_fill<<<dim3(2048), dim3(256), 0, stream>>>((uint4*)h1p, nh4);
    // preconvert emb and Wout to packed bf16 hi/lo planes (once per call)
    preconv<<<dim3(256), dim3(256), 0, stream>>>(emb,  embcv, NVOC);
    preconv<<<dim3(256), dim3(256), 0, stream>>>(Wout, wcvo,  NVOC);

    hipFuncSetAttribute(reinterpret_cast<const void*>(lstm_fused),
                        hipFuncAttributeMaxDynamicSharedMemorySize, FLDS);

    // fused two-layer recurrence with embedded xg0 (no standalone xg GEMM)
    lstm_fused<<<dim3(NWG), dim3(512), FLDS, stream>>>(
        x, embcv, Wih0, Whh0, bih0, bhh0, Wih1, Whh1, bih1, bhh1, h1p, h2p);

    // output projection from packed h2 and preconverted Wout (2-pass)
    gemm_pk<<<dim3(20, 512), dim3(256), 0, stream>>>(h2p, wcvo, bout, out, NVOC);
}

// Round 15
// 3060.600 us; speedup vs baseline: 1.0349x; 1.0349x over previous
//
#include <hip/hip_runtime.h>
#include <cstdint>
#include <cstddef>

namespace {

constexpr int H    = 300;
constexpr int B    = 128;
constexpr int T    = 512;
constexpr int NVOC = 2514;
constexpr int KP   = 304;    // padded K pitch for packed bf16 hi/lo planes

typedef __attribute__((ext_vector_type(8))) short  short8;
typedef __attribute__((ext_vector_type(4))) float  f32x4;

__device__ __forceinline__ float sigm(float x)     { return 1.f / (1.f + __expf(-x)); }
__device__ __forceinline__ float tanhfast(float x) { return 1.f - 2.f / (__expf(2.f*x) + 1.f); }

__device__ __forceinline__ unsigned short bf16_rn(float f) {
    unsigned u = __float_as_uint(f);
    u += 0x7FFFu + ((u >> 16) & 1u);
    return (unsigned short)(u >> 16);
}
__device__ __forceinline__ float bf16_f(unsigned short s) {
    return __uint_as_float(((unsigned)s) << 16);
}
// packed value = bf16hi | (bf16lo << 16)
__device__ __forceinline__ unsigned pack_hl(float v) {
    const unsigned short hi = bf16_rn(v);
    const unsigned short lo = bf16_rn(v - bf16_f(hi));
    return (unsigned)hi | ((unsigned)lo << 16);
}

// packed h layout: idx(t, hg, b, u) = ((t*15 + hg)*128 + b)*20 + u   (u32 elems)
constexpr int TSEG = 15 * 128 * 20;   // u32 per t-slice (38400)

// sentinel: low16 = 0x7FB0 is a bf16 NaN -> impossible as the hi-plane of |h|<1
constexpr unsigned SENTP = 0x7FB07FB0u;

// ---------------------------------------------------------------------------
// Sentinel fill for packed h buffers
// ---------------------------------------------------------------------------
__global__ __launch_bounds__(256)
void sentinel_fill(uint4* __restrict__ p, size_t n4)
{
    const uint4 s = make_uint4(SENTP, SENTP, SENTP, SENTP);
    size_t i = (size_t)blockIdx.x * blockDim.x + threadIdx.x;
    const size_t stride = (size_t)gridDim.x * blockDim.x;
    for (; i < n4; i += stride) p[i] = s;
}

// ---------------------------------------------------------------------------
// Preconvert fp32 [rows][300] -> packed u32 [rows][KP] (hi|lo<<16), pad 0.
// ---------------------------------------------------------------------------
__global__ __launch_bounds__(256)
void preconv(const float* __restrict__ src, unsigned* __restrict__ dst, int rows)
{
    const size_t n = (size_t)rows * KP;
    for (size_t i = (size_t)blockIdx.x * 256 + threadIdx.x; i < n;
         i += (size_t)gridDim.x * 256) {
        const int c = (int)(i % KP), r = (int)(i / KP);
        dst[i] = (c < H) ? pack_hl(src[(size_t)r * H + c]) : 0u;
    }
}

// ---------------------------------------------------------------------------
// Logits GEMM v15: T-MAJOR m-tiles. Round-14's neutral 2-pass result showed
// gemm_pk is not MFMA/staging-bound; the candidate binder is the AMODE-3
// A-gather (15 x 80B scattered pieces per row, rows 153.6 KB apart -> ~2.5x
// line overfetch on 1.57 GB of L3 traffic). Fix: m-tile = ONE t-slice x all
// 128 b. Within slice t, chunk hg is a contiguous 10 KB run over (b,u) ->
// A-staging reads 100%-utilized sequential lines; the 20 n-blocks sharing a
// slice launch adjacently (x-fastest) for L2 reuse. Epilogue: tile row b ->
// out row b*512 + t. Same values, same store-line efficiency; pure remap.
// ---------------------------------------------------------------------------
__global__ __launch_bounds__(256)
void gemm_pk(const unsigned* __restrict__ Apk, const unsigned* __restrict__ Wpk,
             const float* __restrict__ b1, float* __restrict__ out, int N)
{
    __shared__ __align__(16) unsigned short Ah[128][40], Al[128][40];
    __shared__ __align__(16) unsigned short Wh[128][40];

    const int tid = threadIdx.x;
    const int tt = blockIdx.y;            // t-slice = m-tile
    const int n0 = blockIdx.x * 128;
    const int rl = tid >> 1, cb = (tid & 1) * 16;

    // A row rl = batch index b within slice tt; chunk hg at +hg*2560 + b*20
    const unsigned* aptr = Apk + (size_t)tt * TSEG + rl * 20;
    const int nrow = n0 + rl;
    const unsigned* wptr = Wpk + (size_t)nrow * KP;
    const bool nok = (nrow < N);

    const int wv = tid >> 6, lane = tid & 63;
    const int mw = (wv >> 1) * 64, nw = (wv & 1) * 64;
    const int kg = lane >> 4, mm = lane & 15;

    f32x4 acc[4][4];
#pragma unroll
    for (int i = 0; i < 4; ++i)
#pragma unroll
        for (int j = 0; j < 4; ++j) acc[i][j] = (f32x4){0.f, 0.f, 0.f, 0.f};

    for (int kt = 0; kt < 10; ++kt) {
        uint4 pa[4], pw[4];
#pragma unroll
        for (int j = 0; j < 4; ++j) {
            const int col = kt * 32 + cb + j * 4;
            // col%20 in {0,4,8,12,16}: every uint4 stays inside one 20-u32 chunk
            pa[j] = (col < 300)
                  ? *(const uint4*)(aptr + (col / 20) * 2560 + col % 20)
                  : make_uint4(0, 0, 0, 0);
            pw[j] = (nok && col < KP) ? *(const uint4*)(wptr + col)
                                      : make_uint4(0, 0, 0, 0);
        }
        __syncthreads();
#pragma unroll
        for (int j = 0; j < 4; ++j) {
            const int cc = cb + j * 4;
            *(uint2*)&Ah[rl][cc] = make_uint2((pa[j].x & 0xFFFFu) | (pa[j].y << 16),
                                              (pa[j].z & 0xFFFFu) | (pa[j].w << 16));
            *(uint2*)&Al[rl][cc] = make_uint2((pa[j].x >> 16) | (pa[j].y & 0xFFFF0000u),
                                              (pa[j].z >> 16) | (pa[j].w & 0xFFFF0000u));
            *(uint2*)&Wh[rl][cc] = make_uint2((pw[j].x & 0xFFFFu) | (pw[j].y << 16),
                                              (pw[j].z & 0xFFFFu) | (pw[j].w << 16));
        }
        __syncthreads();

        short8 fah[4], fal[4], fbh[4];
#pragma unroll
        for (int f = 0; f < 4; ++f) {
            fah[f] = *(const short8*)&Ah[mw + f*16 + mm][kg*8];
            fal[f] = *(const short8*)&Al[mw + f*16 + mm][kg*8];
            fbh[f] = *(const short8*)&Wh[nw + f*16 + mm][kg*8];
        }
#pragma unroll
        for (int mf = 0; mf < 4; ++mf)
#pragma unroll
            for (int nf = 0; nf < 4; ++nf) {
                acc[mf][nf] = __builtin_amdgcn_mfma_f32_16x16x32_bf16(fah[mf], fbh[nf], acc[mf][nf], 0, 0, 0);
                acc[mf][nf] = __builtin_amdgcn_mfma_f32_16x16x32_bf16(fal[mf], fbh[nf], acc[mf][nf], 0, 0, 0);
            }
    }

    float bias[4];
#pragma unroll
    for (int nf = 0; nf < 4; ++nf) {
        const int n = n0 + nw + nf*16 + mm;
        bias[nf] = (n < N) ? b1[n] : 0.f;
    }
    const int qr = lane >> 4;
#pragma unroll
    for (int mf = 0; mf < 4; ++mf) {
        const int b0 = mw + mf*16 + qr*4;         // tile row = batch index
        float* orow = out + ((size_t)b0 * T + tt) * N;   // out row = b*512 + t
#pragma unroll
        for (int nf = 0; nf < 4; ++nf) {
            const int n = n0 + nw + nf*16 + mm;
            if (n < N) {
#pragma unroll
                for (int r = 0; r < 4; ++r)
                    orow[(size_t)r * T * N + n] = acc[mf][nf][r] + bias[nf];
            }
        }
    }
}

// ---------------------------------------------------------------------------
// v15 fused recurrence — UNCHANGED from rounds 13/14 (protocol floor,
// 4.81 us/iter x 513).
// ---------------------------------------------------------------------------
constexpr int HGC = 15;
constexpr int BGC = 16;
constexpr int NWG = HGC * BGC;   // 240
constexpr int A2OFF  = 20480;    // h2 region within a parity
constexpr int EOFF   = 40960;    // e region within a parity
constexpr int APARF  = 61440;    // bytes per parity (h1 + h2 + e)
constexpr int GDOFF  = 2 * APARF;            // 122880
constexpr int TOKOFF = GDOFF + 10*8*16*4;    // 128000
constexpr int FLDS   = TOKOFF + 8*512*4;     // 144384 B

struct StageCtx {
    size_t   src64[5];
    int      aoffHi[5];
    unsigned pend0;
};

__device__ __forceinline__ void stage_init(StageCtx& S, int lane, int bg,
                                           int base_hg, int nchunks, int region)
{
    const int words = nchunks * 80;   // 80 u64-pairs per (hg,bg) chunk
    S.pend0 = 0;
#pragma unroll
    for (int j = 0; j < 5; ++j) {
        const int s = lane + 64 * j;
        const bool ok = (s < words);
        const int chunk = ok ? s / 80 : 0, rem = ok ? s % 80 : 0;
        const int hg = base_hg + chunk;
        S.src64[j] = (size_t)(hg * 128 + bg * 8) * 10 + rem;
        const int u2 = rem * 2, b_loc = u2 / 20, u = u2 % 20;
        const int k = hg * 20 + u;
        S.aoffHi[j] = region + ((k >> 5) * 8 + ((k >> 3) & 3)) * 256
                    + b_loc * 16 + (k & 7) * 2;
        if (ok) S.pend0 |= 1u << j;
    }
}

__device__ __forceinline__ void stage_poll(const StageCtx& S,
                                           const unsigned* __restrict__ slice,
                                           unsigned char* Ap)
{
    const unsigned long long* s64 = (const unsigned long long*)slice;
    unsigned long long val[5];
    unsigned pend = S.pend0;
    while (__any(pend != 0)) {
        unsigned long long w[5];
#pragma unroll
        for (int j = 0; j < 5; ++j)
            if (pend & (1u << j))
                w[j] = __hip_atomic_load(s64 + S.src64[j], __ATOMIC_RELAXED,
                                         __HIP_MEMORY_SCOPE_AGENT);
#pragma unroll
        for (int j = 0; j < 5; ++j)
            if (pend & (1u << j)) {
                const unsigned long long x = w[j];
                if ((unsigned)x != SENTP && (unsigned)(x >> 32) != SENTP) {
                    val[j] = x; pend &= ~(1u << j);
                }
            }
    }
#pragma unroll
    for (int j = 0; j < 5; ++j)
        if (S.pend0 & (1u << j)) {
            const unsigned p0 = (unsigned)val[j], p1 = (unsigned)(val[j] >> 32);
            *(unsigned*)(Ap + S.aoffHi[j])        = (p0 & 0xFFFFu) | (p1 << 16);
            *(unsigned*)(Ap + S.aoffHi[j] + 1024) = (p0 >> 16) | (p1 & 0xFFFF0000u);
        }
}

struct ECtx { int b[3]; int koff[3]; int aoff[3]; bool ok[3]; };

__device__ __forceinline__ void estage_init(ECtx& E, int tid)
{
#pragma unroll
    for (int j = 0; j < 3; ++j) {
        const int es = tid + 512 * j;
        E.ok[j] = (es < 1216);   // 8 b x 152 k-pairs (incl. 2 zero-pad pairs)
        const int bb = E.ok[j] ? es / 152 : 0;
        const int kp = E.ok[j] ? es % 152 : 0;
        const int k  = kp * 2;
        E.b[j]    = bb;
        E.koff[j] = k;
        E.aoff[j] = EOFF + ((k >> 5) * 8 + ((k >> 3) & 3)) * 256
                  + bb * 16 + (k & 7) * 2;
    }
}

__device__ __forceinline__ void estage(const ECtx& E, const int* __restrict__ tokL,
                                       const unsigned* __restrict__ embcv, int it,
                                       unsigned char* Ap)
{
#pragma unroll
    for (int j = 0; j < 3; ++j)
        if (E.ok[j]) {
            const int tok = tokL[E.b[j] * 512 + it];
            const unsigned long long w = *(const unsigned long long*)
                (embcv + (size_t)tok * KP + E.koff[j]);
            const unsigned p0 = (unsigned)w, p1 = (unsigned)(w >> 32);
            *(unsigned*)(Ap + E.aoff[j])        = (p0 & 0xFFFFu) | (p1 << 16);
            *(unsigned*)(Ap + E.aoff[j] + 1024) = (p0 >> 16) | (p1 & 0xFFFF0000u);
        }
}

// ---- L0 wave: one n-tile (4 units); e@Wih0 (3-pass) + h1@Whh0 (2-pass) ----
__device__ void fused_L0(int lane, int nt, int hg, int bg,
                         const unsigned* __restrict__ embcv,
                         const float* __restrict__ Wih0,
                         const float* __restrict__ Whh0,
                         const float* __restrict__ bih0,
                         const float* __restrict__ bhh0,
                         unsigned* __restrict__ h1p,
                         const unsigned* __restrict__ ssrc, int sreg, int sbase,
                         int snch, int sdel,
                         const ECtx& E, const int* __restrict__ tokL,
                         unsigned char* __restrict__ Abuf, float (*gd)[8][16])
{
    const int kg = lane >> 4, mm = lane & 15;

    short8 bhh[10], bih[10], bil[10];
#pragma unroll
    for (int kt = 0; kt < 10; ++kt) {
        const int c = nt * 16 + mm;
        const int grow = (c & 3) * H + hg * 20 + (c >> 2);
        short8 h_, ih_, il_;
#pragma unroll
        for (int e = 0; e < 8; ++e) {
            const int k = kt * 32 + kg * 8 + e;
            const float vh = (k < H) ? Whh0[(size_t)grow * H + k] : 0.f;
            const float vi = (k < H) ? Wih0[(size_t)grow * H + k] : 0.f;
            h_[e] = (short)bf16_rn(vh);
            const unsigned short i16 = bf16_rn(vi);
            ih_[e] = (short)i16;
            il_[e] = (short)bf16_rn(vi - bf16_f(i16));
        }
        bhh[kt] = h_; bih[kt] = ih_; bil[kt] = il_;
    }

    StageCtx S; stage_init(S, lane, bg, sbase, snch, sreg);

    const bool upd = lane < 32;
    const int b_u = lane >> 2, u4 = lane & 3;
    const int u_loc = nt * 4 + u4;
    float bias[4];
#pragma unroll
    for (int g = 0; g < 4; ++g)
        bias[g] = bih0[g * H + hg * 20 + u_loc] + bhh0[g * H + hg * 20 + u_loc];
    float cst = 0.f;
    unsigned* hst = h1p + ((size_t)hg * 128 + bg * 8 + b_u) * 20 + u_loc;

    for (int it = 0; it <= T; ++it) {
        unsigned char* Ap = Abuf + (it & 1) * APARF;
        if (it < T) estage(E, tokL, embcv, it, Ap);
        if (it >= sdel) stage_poll(S, ssrc + (size_t)(it - sdel) * TSEG, Ap);
        __syncthreads();

        if (it < T) {
            f32x4 acc = (f32x4){0.f, 0.f, 0.f, 0.f};
#pragma unroll
            for (int kt = 0; kt < 10; ++kt) {
                const int boff = (kt * 8 + kg) * 256 + mm * 16;
                const short8 eh = *(const short8*)(Ap + EOFF + boff);
                const short8 el = *(const short8*)(Ap + EOFF + boff + 1024);
                const short8 hh = *(const short8*)(Ap + boff);
                const short8 hl = *(const short8*)(Ap + boff + 1024);
                acc = __builtin_amdgcn_mfma_f32_16x16x32_bf16(eh, bih[kt], acc, 0, 0, 0);
                acc = __builtin_amdgcn_mfma_f32_16x16x32_bf16(el, bih[kt], acc, 0, 0, 0);
                acc = __builtin_amdgcn_mfma_f32_16x16x32_bf16(eh, bil[kt], acc, 0, 0, 0);
                acc = __builtin_amdgcn_mfma_f32_16x16x32_bf16(hh, bhh[kt], acc, 0, 0, 0);
                acc = __builtin_amdgcn_mfma_f32_16x16x32_bf16(hl, bhh[kt], acc, 0, 0, 0);
            }
            if (lane < 32) {
                const int br = (lane >> 4) * 4;
#pragma unroll
                for (int r = 0; r < 4; ++r) gd[nt][br + r][mm] = acc[r];
            }
            if (upd) {
                const float* g4 = &gd[nt][b_u][u4 * 4];
                const float gi = bias[0] + g4[0], gf = bias[1] + g4[1];
                const float gz = bias[2] + g4[2], go = bias[3] + g4[3];
                const float iG = sigm(gi), fG = sigm(gf);
                const float zG = tanhfast(gz), oG = sigm(go);
                cst = fmaf(fG, cst, iG * zG);
                const float hv = oG * tanhfast(cst);
                __hip_atomic_store(hst + (size_t)it * TSEG, pack_hl(hv),
                                   __ATOMIC_RELAXED, __HIP_MEMORY_SCOPE_AGENT);
            }
        }
    }
}

// ---- L1 wave: NTL tiles; h1@Wih1 (2-pass) + h2@Whh1 (2-pass) per tile ------
template<int NTL>
__device__ void fused_L1(int lane, int t0, int hg, int bg,
                         const unsigned* __restrict__ embcv,
                         const float* __restrict__ Wih1,
                         const float* __restrict__ Whh1,
                         const float* __restrict__ bih1,
                         const float* __restrict__ bhh1,
                         unsigned* __restrict__ h2p,
                         const unsigned* __restrict__ ssrc, int sreg, int sbase,
                         int snch, int sdel,
                         const ECtx& E, const int* __restrict__ tokL,
                         unsigned char* __restrict__ Abuf, float (*gd)[8][16])
{
    const int kg = lane >> 4, mm = lane & 15;

    short8 bi[NTL][10], bh[NTL][10];
#pragma unroll
    for (int t = 0; t < NTL; ++t)
#pragma unroll
        for (int kt = 0; kt < 10; ++kt) {
            const int c = (t0 + t) * 16 + mm;
            const int grow = (c & 3) * H + hg * 20 + (c >> 2);
            short8 i_, h_;
#pragma unroll
            for (int e = 0; e < 8; ++e) {
                const int k = kt * 32 + kg * 8 + e;
                i_[e] = (short)bf16_rn((k < H) ? Wih1[(size_t)grow * H + k] : 0.f);
                h_[e] = (short)bf16_rn((k < H) ? Whh1[(size_t)grow * H + k] : 0.f);
            }
            bi[t][kt] = i_; bh[t][kt] = h_;
        }

    StageCtx S; stage_init(S, lane, bg, sbase, snch, sreg);

    const bool upd = lane < NTL * 32;
    const int tile = lane >> 5, lidx = lane & 31;
    const int b_u = lidx >> 2, u4 = lidx & 3;
    const int ntg = t0 + ((NTL > 1) ? tile : 0);
    const int u_loc = ntg * 4 + u4;
    float bias[4];
#pragma unroll
    for (int g = 0; g < 4; ++g)
        bias[g] = bih1[g * H + hg * 20 + u_loc] + bhh1[g * H + hg * 20 + u_loc];
    float cst = 0.f;
    unsigned* hst = h2p + ((size_t)hg * 128 + bg * 8 + b_u) * 20 + u_loc;

    for (int it = 0; it <= T; ++it) {
        unsigned char* Ap = Abuf + (it & 1) * APARF;
        if (it < T) estage(E, tokL, embcv, it, Ap);
        if (it >= sdel) stage_poll(S, ssrc + (size_t)(it - sdel) * TSEG, Ap);
        __syncthreads();

        if (it >= 1) {
            f32x4 acc[NTL];
#pragma unroll
            for (int t = 0; t < NTL; ++t) acc[t] = (f32x4){0.f, 0.f, 0.f, 0.f};
#pragma unroll
            for (int kt = 0; kt < 10; ++kt) {
                const int boff = (kt * 8 + kg) * 256 + mm * 16;
                const short8 x1h = *(const short8*)(Ap + boff);
                const short8 x1l = *(const short8*)(Ap + boff + 1024);
                const short8 x2h = *(const short8*)(Ap + A2OFF + boff);
                const short8 x2l = *(const short8*)(Ap + A2OFF + boff + 1024);
#pragma unroll
                for (int t = 0; t < NTL; ++t) {
                    acc[t] = __builtin_amdgcn_mfma_f32_16x16x32_bf16(x1h, bi[t][kt], acc[t], 0, 0, 0);
                    acc[t] = __builtin_amdgcn_mfma_f32_16x16x32_bf16(x1l, bi[t][kt], acc[t], 0, 0, 0);
                    acc[t] = __builtin_amdgcn_mfma_f32_16x16x32_bf16(x2h, bh[t][kt], acc[t], 0, 0, 0);
                    acc[t] = __builtin_amdgcn_mfma_f32_16x16x32_bf16(x2l, bh[t][kt], acc[t], 0, 0, 0);
                }
            }
            if (lane < 32) {
                const int br = (lane >> 4) * 4;
#pragma unroll
                for (int t = 0; t < NTL; ++t)
#pragma unroll
                    for (int r = 0; r < 4; ++r) gd[5 + t0 + t][br + r][mm] = acc[t][r];
            }
            if (upd) {
                const float* g4 = &gd[5 + ntg][b_u][u4 * 4];
                const float gi = bias[0] + g4[0], gf = bias[1] + g4[1];
                const float gz = bias[2] + g4[2], go = bias[3] + g4[3];
                const float iG = sigm(gi), fG = sigm(gf);
                const float zG = tanhfast(gz), oG = sigm(go);
                cst = fmaf(fG, cst, iG * zG);
                const float hv = oG * tanhfast(cst);
                __hip_atomic_store(hst + (size_t)(it - 1) * TSEG, pack_hl(hv),
                                   __ATOMIC_RELAXED, __HIP_MEMORY_SCOPE_AGENT);
            }
        }
    }
}

__global__ __launch_bounds__(512, 2)
void lstm_fused(const int* __restrict__ x,
                const unsigned* __restrict__ embcv,
                const float* __restrict__ Wih0, const float* __restrict__ Whh0,
                const float* __restrict__ bih0, const float* __restrict__ bhh0,
                const float* __restrict__ Wih1, const float* __restrict__ Whh1,
                const float* __restrict__ bih1, const float* __restrict__ bhh1,
                unsigned* __restrict__ h1p, unsigned* __restrict__ h2p)
{
    extern __shared__ unsigned char smem[];
    unsigned char* Abuf = smem;
    float (*gd)[8][16] = (float(*)[8][16])(smem + GDOFF);
    int* tokL = (int*)(smem + TOKOFF);

    const int tid = threadIdx.x, wv = tid >> 6, lane = tid & 63;
    const int hg = blockIdx.x % HGC, bg = blockIdx.x / HGC;

    for (int i = tid; i < FLDS / 16; i += 512)
        ((uint4*)smem)[i] = make_uint4(0, 0, 0, 0);
    __syncthreads();
    // preload tokens for this block's 8 batch rows: tokL[b][t]
    for (int idx = tid; idx < 8 * 512; idx += 512) {
        const int b = idx >> 9, tt = idx & 511;
        tokL[idx] = x[(size_t)(bg * 8 + b) * T + tt];
    }
    __syncthreads();

    ECtx E; estage_init(E, tid);

    // staging role: wv0-3 -> h1 quarters (d=1), wv4-7 -> h2 quarters (d=2)
    const int      sreg  = (wv < 4) ? 0 : A2OFF;
    const unsigned* ssrc = (wv < 4) ? h1p : h2p;
    const int      sbase = (wv & 3) * 4;
    const int      snch  = ((wv & 3) == 3) ? 3 : 4;
    const int      sdel  = (wv < 4) ? 1 : 2;

    if (wv < 5)
        fused_L0(lane, wv, hg, bg, embcv, Wih0, Whh0, bih0, bhh0, h1p,
                 ssrc, sreg, sbase, snch, sdel, E, tokL, Abuf, gd);
    else if (wv == 5)
        fused_L1<2>(lane, 0, hg, bg, embcv, Wih1, Whh1, bih1, bhh1, h2p,
                    ssrc, sreg, sbase, snch, sdel, E, tokL, Abuf, gd);
    else if (wv == 6)
        fused_L1<2>(lane, 2, hg, bg, embcv, Wih1, Whh1, bih1, bhh1, h2p,
                    ssrc, sreg, sbase, snch, sdel, E, tokL, Abuf, gd);
    else
        fused_L1<1>(lane, 4, hg, bg, embcv, Wih1, Whh1, bih1, bhh1, h2p,
                    ssrc, sreg, sbase, snch, sdel, E, tokL, Abuf, gd);
}

} // anonymous namespace

// ---------------------------------------------------------------------------
extern "C" void kernel_launch(void* const* d_in, const int* in_sizes, int n_in,
                              void* d_out, int out_size, void* d_ws, size_t ws_size,
                              hipStream_t stream)
{
    const int*   x    = (const int*)  d_in[0];
    const float* emb  = (const float*)d_in[1];
    const float* Wih0 = (const float*)d_in[2];
    const float* Whh0 = (const float*)d_in[3];
    const float* bih0 = (const float*)d_in[4];
    const float* bhh0 = (const float*)d_in[5];
    const float* Wih1 = (const float*)d_in[6];
    const float* Whh1 = (const float*)d_in[7];
    const float* bih1 = (const float*)d_in[8];
    const float* bhh1 = (const float*)d_in[9];
    const float* Wout = (const float*)d_in[10];
    const float* bout = (const float*)d_in[11];

    float* out = (float*)d_out;

    // d_ws layout: h1p, h2p (packed u32, 78.64 MB each), embcv, wcvo
    unsigned* h1p   = (unsigned*)d_ws;
    unsigned* h2p   = h1p + (size_t)T * TSEG;
    unsigned* embcv = h2p + (size_t)T * TSEG;
    unsigned* wcvo  = embcv + (size_t)NVOC * KP;

    // sentinel-fill both packed h buffers (data-as-flag protocol)
    const size_t nh4 = 2 * (size_t)T * TSEG / 4;
    sentinel_fill<<<dim3(2048), dim3(256), 0, stream>>>((uint4*)h1p, nh4);
    // preconvert emb and Wout to packed bf16 hi/lo planes (once per call)
    preconv<<<dim3(256), dim3(256), 0, stream>>>(emb,  embcv, NVOC);
    preconv<<<dim3(256), dim3(256), 0, stream>>>(Wout, wcvo,  NVOC);

    hipFuncSetAttribute(reinterpret_cast<const void*>(lstm_fused),
                        hipFuncAttributeMaxDynamicSharedMemorySize, FLDS);

    // fused two-layer recurrence with embedded xg0 (no standalone xg GEMM)
    lstm_fused<<<dim3(NWG), dim3(512), FLDS, stream>>>(
        x, embcv, Wih0, Whh0, bih0, bhh0, Wih1, Whh1, bih1, bhh1, h1p, h2p);

    // output projection: t-major m-tiles (coalesced A), 2-pass
    gemm_pk<<<dim3(20, 512), dim3(256), 0, stream>>>(h2p, wcvo, bout, out, NVOC);
}